// Round 11
// baseline (95.437 us; speedup 1.0000x reference)
//
#include <hip/hip_runtime.h>
#include <math.h>

#define IN_DIM 512
#define OUT_DIM 128
#define BM 64
#define BK 64
#define NKT (IN_DIM / BK)  // 8

typedef __attribute__((ext_vector_type(8))) __bf16 bf16x8;
typedef __attribute__((ext_vector_type(2))) __bf16 bf16x2;
typedef __attribute__((ext_vector_type(4))) float f32x4;
typedef __attribute__((ext_vector_type(2))) float f32x2;

// Manual RNE fp32->bf16 (bit ops) — r5-proven codegen for epilogue/prep.
__device__ inline unsigned short f2bf(float f) {
    unsigned u = __float_as_uint(f);
    u += 0x7FFFu + ((u >> 16) & 1u);  // round-to-nearest-even
    return (unsigned short)(u >> 16);
}

// In-register fp32x8 -> bf16x8 via native paired casts (v_cvt_pk_bf16_f32),
// consumed immediately by MFMA (short live ranges).
__device__ inline bf16x8 cvt8(const f32x4& lo, const f32x4& hi) {
    bf16x2 p0 = {(__bf16)lo.x, (__bf16)lo.y};
    bf16x2 p1 = {(__bf16)lo.z, (__bf16)lo.w};
    bf16x2 p2 = {(__bf16)hi.x, (__bf16)hi.y};
    bf16x2 p3 = {(__bf16)hi.z, (__bf16)hi.w};
    uint4 u = {__builtin_bit_cast(unsigned, p0), __builtin_bit_cast(unsigned, p1),
               __builtin_bit_cast(unsigned, p2), __builtin_bit_cast(unsigned, p3)};
    return __builtin_bit_cast(bf16x8, u);
}

// async global->LDS, 16B per lane (dest = wave-uniform base + lane*16)
__device__ inline void gload_lds16(const void* g, void* l) {
    __builtin_amdgcn_global_load_lds(
        (const __attribute__((address_space(1))) void*)g,
        (__attribute__((address_space(3))) void*)l, 16, 0, 0);
}

// w [512][128] f32 -> wt2 k-interleaved bf16: wt2[(k>>3)*128 + n][k&7]
__global__ void wt2_kernel(const float* __restrict__ w, unsigned short* __restrict__ wt2) {
    int idx = blockIdx.x * 256 + threadIdx.x;  // 65536 total
    int k = idx >> 7;
    int n = idx & 127;
    wt2[(((k >> 3) * 128) + n) * 8 + (k & 7)] = f2bf(w[idx]);
}

// ---------------------------------------------------------------------------
// z_bf[M,128](bf16) = x[M,512] @ w[512,128] via bf16 MFMA, fp32 accumulate.
// DEPTH-2 DMA pipeline (T3/T4 structurally): 4 x 16 KB LDS buffers; DMA for
// tile t+2 issued at iteration t; counted `s_waitcnt vmcnt(8)` + RAW
// s_barrier (never drain to 0 mid-loop) so 8 DMA loads stay in flight across
// the barrier; tail 8 -> 4 -> 0. Race-free: buffer (t+2)&3 was last read in
// compute(t-2), finished by all waves before iteration (t-1)'s barrier.
// Both-sides XOR swizzle on A (rule 21). fp32->bf16 on the consume side.
// B fragments direct from L2-resident wt2. 4 waves (2x2), wave = 32x64 out.
// ---------------------------------------------------------------------------
__global__ __launch_bounds__(256, 2) void gemm_mfma(const float* __restrict__ x,
                                                    const unsigned short* __restrict__ wt2,
                                                    unsigned short* __restrict__ zb,
                                                    int M) {
    __shared__ float sA[4][BM * BK / 4 * 4];  // 4 x 16 KB fp32, col-swizzled
    char* const pAb = (char*)sA;

    const int tid  = threadIdx.x;
    const int lane = tid & 63;
    const int wid  = tid >> 6;
    const int wm   = wid >> 1;  // 0..1
    const int wn   = wid & 1;   // 0..1
    const int block_row = blockIdx.x * BM;

    const int fr  = lane & 15;  // fragment row (A) / col (B)
    const int fk4 = lane >> 4;  // k-octet group 0..3

    f32x4 acc[2][4];
#pragma unroll
    for (int i = 0; i < 2; ++i)
#pragma unroll
        for (int j = 0; j < 4; ++j) acc[i][j] = (f32x4){0.f, 0.f, 0.f, 0.f};

    // staging map: chunk c = wid*4+i covers LDS [c*1024, c*1024+1024)
    // = rows 4c..4c+3 (256 B/row). Lane: row 4c+(lane>>4), bytes (lane&15)*16.
    const int s_row = lane >> 4;         // 0..3 within chunk
    const int s_cb  = (lane & 15) * 16;  // 0..240

    // fragment-read map (logical row, swizzled column)
    const int rowa0 = wm * 32 + fr;
    const int rowa1 = rowa0 + 16;
    const int swz7  = (fr & 7) << 5;

    // B per-lane base in wt2 (element units)
    const unsigned short* pb = wt2 + fk4 * 1024 + (wn * 64 + fr) * 8;

    // issue one tile's 4 DMA chunks (tile T -> buffer B)
#define STAGE(T, B)                                                              \
    {                                                                            \
        _Pragma("unroll") for (int i = 0; i < 4; ++i) {                          \
            const int rr = (wid * 4 + i) * 4 + s_row;                            \
            int grow = block_row + rr;                                           \
            grow = (grow < M) ? grow : (M - 1);                                  \
            const char* src = (const char*)x + (size_t)grow * 2048 +             \
                              (T) * 256 + (s_cb ^ ((rr & 7) << 5));              \
            gload_lds16(src, pAb + (B) * 16384 + (wid * 4 + i) * 1024);          \
        }                                                                        \
    }

    // counted wait + raw barrier (rule #18 fences)
#define WAITB(N)                                                                 \
    {                                                                            \
        asm volatile("s_waitcnt vmcnt(" #N ")" ::: "memory");                    \
        __builtin_amdgcn_sched_barrier(0);                                       \
        __builtin_amdgcn_s_barrier();                                            \
        __builtin_amdgcn_sched_barrier(0);                                       \
    }

    // compute tile T from buffer B
#define COMP(T, B)                                                               \
    {                                                                            \
        const char* pT = pAb + (B) * 16384;                                      \
        _Pragma("unroll") for (int ks = 0; ks < 2; ++ks) {                       \
            const int cb0 = ks * 128 + fk4 * 32;                                 \
            f32x4 lo0 = *(const f32x4*)(pT + rowa0 * 256 + (cb0 ^ swz7));        \
            f32x4 hi0 = *(const f32x4*)(pT + rowa0 * 256 + (cb0 ^ swz7) + 16);   \
            f32x4 lo1 = *(const f32x4*)(pT + rowa1 * 256 + (cb0 ^ swz7));        \
            f32x4 hi1 = *(const f32x4*)(pT + rowa1 * 256 + (cb0 ^ swz7) + 16);   \
            bf16x8 af0 = cvt8(lo0, hi0);                                         \
            bf16x8 af1 = cvt8(lo1, hi1);                                         \
            bf16x8 bv0 = *(const bf16x8*)(pb + (T) * 8192 + ks * 4096 + 0);      \
            bf16x8 bv1 = *(const bf16x8*)(pb + (T) * 8192 + ks * 4096 + 128);    \
            bf16x8 bv2 = *(const bf16x8*)(pb + (T) * 8192 + ks * 4096 + 256);    \
            bf16x8 bv3 = *(const bf16x8*)(pb + (T) * 8192 + ks * 4096 + 384);    \
            acc[0][0] = __builtin_amdgcn_mfma_f32_16x16x32_bf16(af0, bv0, acc[0][0], 0, 0, 0); \
            acc[0][1] = __builtin_amdgcn_mfma_f32_16x16x32_bf16(af0, bv1, acc[0][1], 0, 0, 0); \
            acc[0][2] = __builtin_amdgcn_mfma_f32_16x16x32_bf16(af0, bv2, acc[0][2], 0, 0, 0); \
            acc[0][3] = __builtin_amdgcn_mfma_f32_16x16x32_bf16(af0, bv3, acc[0][3], 0, 0, 0); \
            acc[1][0] = __builtin_amdgcn_mfma_f32_16x16x32_bf16(af1, bv0, acc[1][0], 0, 0, 0); \
            acc[1][1] = __builtin_amdgcn_mfma_f32_16x16x32_bf16(af1, bv1, acc[1][1], 0, 0, 0); \
            acc[1][2] = __builtin_amdgcn_mfma_f32_16x16x32_bf16(af1, bv2, acc[1][2], 0, 0, 0); \
            acc[1][3] = __builtin_amdgcn_mfma_f32_16x16x32_bf16(af1, bv3, acc[1][3], 0, 0, 0); \
        }                                                                        \
    }

    // prologue: 2 tiles in flight
    STAGE(0, 0);
    STAGE(1, 1);

    STAGE(2, 2); WAITB(8); COMP(0, 0);
    STAGE(3, 3); WAITB(8); COMP(1, 1);
    STAGE(4, 0); WAITB(8); COMP(2, 2);
    STAGE(5, 1); WAITB(8); COMP(3, 3);
    STAGE(6, 2); WAITB(8); COMP(4, 0);
    STAGE(7, 3); WAITB(8); COMP(5, 1);
                 WAITB(4); COMP(6, 2);
                 WAITB(0); COMP(7, 3);

#undef STAGE
#undef WAITB
#undef COMP

    // C/D layout: col = lane&15, row = (lane>>4)*4 + reg. Store bf16.
    const int crow0 = (lane >> 4) * 4;
    const int ccol  = lane & 15;
#pragma unroll
    for (int mf = 0; mf < 2; ++mf)
#pragma unroll
        for (int r = 0; r < 4; ++r) {
            const int grow = block_row + wm * 32 + mf * 16 + crow0 + r;
            if (grow < M) {
                unsigned short* zr = zb + (size_t)grow * OUT_DIM + wn * 64 + ccol;
#pragma unroll
                for (int nf = 0; nf < 4; ++nf)
                    zr[nf * 16] = f2bf(acc[mf][nf][r]);
            }
        }
}

// ---------------------------------------------------------------------------
// Decode: out[e] = sigmoid( sum_k z[a_e,k]*z[b_e,k]*w3[k] ), z in bf16.
// 16 lanes per edge, 4 edges/wave, grid-stride UNROLLED x2 (2x MLP).
// ---------------------------------------------------------------------------
__device__ inline float dotw3(const uint4& ua, const uint4& ub, const f32x2* w3v) {
    const unsigned pa[4] = {ua.x, ua.y, ua.z, ua.w};
    const unsigned pb[4] = {ub.x, ub.y, ub.z, ub.w};
    f32x2 vv = (f32x2){0.f, 0.f};
#pragma unroll
    for (int i = 0; i < 4; ++i) {
        f32x2 A = (f32x2){__uint_as_float(pa[i] << 16),
                          __uint_as_float(pa[i] & 0xFFFF0000u)};
        f32x2 B = (f32x2){__uint_as_float(pb[i] << 16),
                          __uint_as_float(pb[i] & 0xFFFF0000u)};
        vv += (A * B) * w3v[i];  // v_pk_mul_f32 + v_pk_fma_f32
    }
    return vv.x + vv.y;
}

__global__ __launch_bounds__(256) void decode_kernel(const unsigned short* __restrict__ zb,
                                                     const int* __restrict__ e1,
                                                     const int* __restrict__ e2,
                                                     const float* __restrict__ w3,
                                                     float* __restrict__ out,
                                                     int E1, int E2) {
    const int tid  = threadIdx.x;
    const int lane = tid & 63;
    const int sub  = lane & 15;   // lane within 16-group
    const int sg   = lane >> 4;   // edge slot within wave (0..3)
    const int Etot = E1 + E2;
    const int nq   = (Etot + 3) >> 2;

    f32x2 w3v[4];
    {
        const float4 wlo = *(const float4*)(w3 + sub * 8);
        const float4 whi = *(const float4*)(w3 + sub * 8 + 4);
        w3v[0] = (f32x2){wlo.x, wlo.y};
        w3v[1] = (f32x2){wlo.z, wlo.w};
        w3v[2] = (f32x2){whi.x, whi.y};
        w3v[3] = (f32x2){whi.z, whi.w};
    }

    const int wave = blockIdx.x * 4 + (tid >> 6);
    const int S    = gridDim.x * 4;  // stride in quads

    for (int q = wave; q < nq; q += 2 * S) {
        const int q2    = q + S;
        const bool has2 = (q2 < nq);

        const int e_a = q * 4 + sg;
        const int e_b = has2 ? (q2 * 4 + sg) : e_a;
        const int ca  = min(e_a, Etot - 1);
        const int cb  = min(e_b, Etot - 1);

        // both index loads up front
        const int2 ia = (ca < E1) ? ((const int2*)e1)[ca] : ((const int2*)e2)[ca - E1];
        const int2 ib = (cb < E1) ? ((const int2*)e1)[cb] : ((const int2*)e2)[cb - E1];

        // all 4 row gathers issued before any math
        const uint4 a1 = *(const uint4*)(zb + (size_t)ia.x * OUT_DIM + sub * 8);
        const uint4 b1 = *(const uint4*)(zb + (size_t)ia.y * OUT_DIM + sub * 8);
        const uint4 a2 = *(const uint4*)(zb + (size_t)ib.x * OUT_DIM + sub * 8);
        const uint4 b2 = *(const uint4*)(zb + (size_t)ib.y * OUT_DIM + sub * 8);

        float v1 = dotw3(a1, b1, w3v);
        float v2 = dotw3(a2, b2, w3v);

        v1 += __shfl_xor(v1, 8);  v2 += __shfl_xor(v2, 8);
        v1 += __shfl_xor(v1, 4);  v2 += __shfl_xor(v2, 4);
        v1 += __shfl_xor(v1, 2);  v2 += __shfl_xor(v2, 2);
        v1 += __shfl_xor(v1, 1);  v2 += __shfl_xor(v2, 1);

        if (sub == 0) {
            if (e_a < Etot) out[e_a] = 1.f / (1.f + __expf(-v1));
            if (has2 && e_b < Etot) out[e_b] = 1.f / (1.f + __expf(-v2));
        }
    }
}

extern "C" void kernel_launch(void* const* d_in, const int* in_sizes, int n_in,
                              void* d_out, int out_size, void* d_ws, size_t ws_size,
                              hipStream_t stream) {
    const float* x  = (const float*)d_in[0];
    const int*   e1 = (const int*)d_in[1];
    const int*   e2 = (const int*)d_in[2];
    const float* w  = (const float*)d_in[3];
    const float* w3 = (const float*)d_in[4];

    float* out = (float*)d_out;

    const int M  = in_sizes[0] / IN_DIM;  // 100000
    const int E1 = in_sizes[1] / 2;       // 300000
    const int E2 = in_sizes[2] / 2;       // 300000

    // workspace: z_bf [M,128] bf16 (25.6 MB), then wt2 [512x128] bf16 (128 KB)
    unsigned short* zbuf = (unsigned short*)d_ws;
    unsigned short* wt2  = zbuf + (size_t)M * OUT_DIM;

    wt2_kernel<<<(IN_DIM * OUT_DIM) / 256, 256, 0, stream>>>(w, wt2);
    gemm_mfma<<<(M + BM - 1) / BM, 256, 0, stream>>>(x, wt2, zbuf, M);
    decode_kernel<<<2048, 256, 0, stream>>>(zbuf, e1, e2, w3, out, E1, E2);
}

// Round 12
// 89.213 us; speedup vs baseline: 1.0698x; 1.0698x over previous
//
#include <hip/hip_runtime.h>
#include <math.h>

#define IN_DIM 512
#define OUT_DIM 128
#define BM 64

typedef __attribute__((ext_vector_type(8))) __bf16 bf16x8;
typedef __attribute__((ext_vector_type(2))) __bf16 bf16x2;
typedef __attribute__((ext_vector_type(4))) float f32x4;
typedef __attribute__((ext_vector_type(2))) float f32x2;

// Manual RNE fp32->bf16 (bit ops) — r5-proven codegen for epilogue/prep.
__device__ inline unsigned short f2bf(float f) {
    unsigned u = __float_as_uint(f);
    u += 0x7FFFu + ((u >> 16) & 1u);  // round-to-nearest-even
    return (unsigned short)(u >> 16);
}

// In-register fp32x8 -> bf16x8 via native paired casts (v_cvt_pk_bf16_f32),
// consumed immediately by MFMA (short live ranges).
__device__ inline bf16x8 cvt8(const f32x4& lo, const f32x4& hi) {
    bf16x2 p0 = {(__bf16)lo.x, (__bf16)lo.y};
    bf16x2 p1 = {(__bf16)lo.z, (__bf16)lo.w};
    bf16x2 p2 = {(__bf16)hi.x, (__bf16)hi.y};
    bf16x2 p3 = {(__bf16)hi.z, (__bf16)hi.w};
    uint4 u = {__builtin_bit_cast(unsigned, p0), __builtin_bit_cast(unsigned, p1),
               __builtin_bit_cast(unsigned, p2), __builtin_bit_cast(unsigned, p3)};
    return __builtin_bit_cast(bf16x8, u);
}

// async global->LDS, 16B per lane (dest = wave-uniform base + lane*16)
__device__ inline void gload_lds16(const void* g, void* l) {
    __builtin_amdgcn_global_load_lds(
        (const __attribute__((address_space(1))) void*)g,
        (__attribute__((address_space(3))) void*)l, 16, 0, 0);
}

// w [512][128] f32 -> wt2 k-interleaved bf16: wt2[(k>>3)*128 + n][k&7]
__global__ void wt2_kernel(const float* __restrict__ w, unsigned short* __restrict__ wt2) {
    int idx = blockIdx.x * 256 + threadIdx.x;  // 65536 total
    int k = idx >> 7;
    int n = idx & 127;
    wt2[(((k >> 3) * 128) + n) * 8 + (k & 7)] = f2bf(w[idx]);
}

// ---------------------------------------------------------------------------
// z_bf[M,128](bf16) = x[M,512] @ w[512,128] via bf16 MFMA, fp32 accumulate.
// WAVE-PRIVATE staging, ZERO barriers. Each wave stages its own 32-row
// A-slice (fp32, BK=32 tiles = 4 KB) via global_load_lds into a private
// double-buffered LDS region; the wn-pair's duplicate x read is L2-absorbed.
// Per-iteration issue order: 4 B-loads(t+1) -> 4 DMAs(t+1) -> vmcnt(8)
// (retires exactly through DMA(t); B(t) is older so its use never drains
// the pipeline) -> compute(t). No __syncthreads anywhere: latency hiding =
// counted vmcnt + 20 free-running waves/CU (32 KB LDS -> 5 blocks/CU).
// Source-side XOR swizzle + matching ds_read XOR -> <=2-way LDS conflicts.
// 4 waves (2x2), wave = 32 rows x 64 cols out.
// ---------------------------------------------------------------------------
__global__ __launch_bounds__(256, 4) void gemm_mfma(const float* __restrict__ x,
                                                    const unsigned short* __restrict__ wt2,
                                                    unsigned short* __restrict__ zb,
                                                    int M) {
    __shared__ float sA[8192];  // 32 KB: 4 waves x 2 bufs x 4 KB, swizzled
    char* const pAb = (char*)sA;

    const int tid  = threadIdx.x;
    const int lane = tid & 63;
    const int wid  = tid >> 6;
    const int wm   = wid >> 1;  // 0..1
    const int wn   = wid & 1;   // 0..1
    const int block_row = blockIdx.x * BM;

    const int fr  = lane & 15;  // fragment row (A) / col (B)
    const int fk4 = lane >> 4;  // k-octet group 0..3

    f32x4 acc[2][4];
#pragma unroll
    for (int i = 0; i < 2; ++i)
#pragma unroll
        for (int j = 0; j < 4; ++j) acc[i][j] = (f32x4){0.f, 0.f, 0.f, 0.f};

    // ---- staging map (per wave, 32 rows x 32 k fp32 = 4 KB = 4 chunks).
    // Chunk i: rows 8i..8i+7. Lane: row-in-chunk = lane>>3, col 16B-slot
    // lane&7. Source col-byte inverse-swizzled by ((lane>>3)&7)<<4.
    const int s_cb = ((lane & 7) * 16) ^ ((lane >> 3) << 4);
    const char* sbase0;
    const char* sbase1;
    const char* sbase2;
    const char* sbase3;
    {
        int r0 = block_row + wm * 32 + 0 * 8 + (lane >> 3); r0 = (r0 < M) ? r0 : (M - 1);
        int r1 = block_row + wm * 32 + 1 * 8 + (lane >> 3); r1 = (r1 < M) ? r1 : (M - 1);
        int r2 = block_row + wm * 32 + 2 * 8 + (lane >> 3); r2 = (r2 < M) ? r2 : (M - 1);
        int r3 = block_row + wm * 32 + 3 * 8 + (lane >> 3); r3 = (r3 < M) ? r3 : (M - 1);
        sbase0 = (const char*)x + (size_t)r0 * 2048 + s_cb;
        sbase1 = (const char*)x + (size_t)r1 * 2048 + s_cb;
        sbase2 = (const char*)x + (size_t)r2 * 2048 + s_cb;
        sbase3 = (const char*)x + (size_t)r3 * 2048 + s_cb;
    }
    char* const wbase = pAb + wid * 8192;  // wave-private 8 KB (2 x 4 KB)

    // ---- fragment-read map (logical row, swizzled column)
    const int swz  = (fr & 7) << 4;
    const int cb0  = (fk4 * 32) ^ swz;
    const int cb1  = (fk4 * 32 + 16) ^ swz;
    const int ra0  = fr * 128;          // mf=0 row byte
    const int ra1  = (fr + 16) * 128;   // mf=1 row byte

    // B per-lane base in wt2 (element units); tile t -> + t*4096
    const unsigned short* pb = wt2 + fk4 * 1024 + (wn * 64 + fr) * 8;

    bf16x8 Be0, Be1, Be2, Be3;  // B regs, even tiles
    bf16x8 Bo0, Bo1, Bo2, Bo3;  // B regs, odd tiles

#define LOADB(T, R0, R1, R2, R3)                        \
    R0 = *(const bf16x8*)(pb + (T) * 4096 + 0);         \
    R1 = *(const bf16x8*)(pb + (T) * 4096 + 128);       \
    R2 = *(const bf16x8*)(pb + (T) * 4096 + 256);       \
    R3 = *(const bf16x8*)(pb + (T) * 4096 + 384);

#define STAGE(T, BUF)                                   \
    gload_lds16(sbase0 + (T) * 128, wbase + (BUF) * 4096 + 0);    \
    gload_lds16(sbase1 + (T) * 128, wbase + (BUF) * 4096 + 1024); \
    gload_lds16(sbase2 + (T) * 128, wbase + (BUF) * 4096 + 2048); \
    gload_lds16(sbase3 + (T) * 128, wbase + (BUF) * 4096 + 3072);

#define WAIT8                                                      \
    __builtin_amdgcn_sched_barrier(0);                             \
    asm volatile("s_waitcnt vmcnt(8)" ::: "memory");               \
    __builtin_amdgcn_sched_barrier(0);

#define WAIT0                                                      \
    __builtin_amdgcn_sched_barrier(0);                             \
    asm volatile("s_waitcnt vmcnt(0)" ::: "memory");               \
    __builtin_amdgcn_sched_barrier(0);

#define COMPT(BUF, B0, B1, B2, B3)                                              \
    {                                                                           \
        const char* pT = wbase + (BUF) * 4096;                                  \
        f32x4 lo0 = *(const f32x4*)(pT + ra0 + cb0);                            \
        f32x4 hi0 = *(const f32x4*)(pT + ra0 + cb1);                            \
        f32x4 lo1 = *(const f32x4*)(pT + ra1 + cb0);                            \
        f32x4 hi1 = *(const f32x4*)(pT + ra1 + cb1);                            \
        bf16x8 af0 = cvt8(lo0, hi0);                                            \
        bf16x8 af1 = cvt8(lo1, hi1);                                            \
        acc[0][0] = __builtin_amdgcn_mfma_f32_16x16x32_bf16(af0, B0, acc[0][0], 0, 0, 0); \
        acc[0][1] = __builtin_amdgcn_mfma_f32_16x16x32_bf16(af0, B1, acc[0][1], 0, 0, 0); \
        acc[0][2] = __builtin_amdgcn_mfma_f32_16x16x32_bf16(af0, B2, acc[0][2], 0, 0, 0); \
        acc[0][3] = __builtin_amdgcn_mfma_f32_16x16x32_bf16(af0, B3, acc[0][3], 0, 0, 0); \
        acc[1][0] = __builtin_amdgcn_mfma_f32_16x16x32_bf16(af1, B0, acc[1][0], 0, 0, 0); \
        acc[1][1] = __builtin_amdgcn_mfma_f32_16x16x32_bf16(af1, B1, acc[1][1], 0, 0, 0); \
        acc[1][2] = __builtin_amdgcn_mfma_f32_16x16x32_bf16(af1, B2, acc[1][2], 0, 0, 0); \
        acc[1][3] = __builtin_amdgcn_mfma_f32_16x16x32_bf16(af1, B3, acc[1][3], 0, 0, 0); \
    }

    // prologue: tile 0 in flight
    LOADB(0, Be0, Be1, Be2, Be3);
    STAGE(0, 0);

#pragma unroll
    for (int p = 0; p < 8; ++p) {
        // t = 2p (even, buf0, Be)
        LOADB(2 * p + 1, Bo0, Bo1, Bo2, Bo3);
        STAGE(2 * p + 1, 1);
        WAIT8;
        COMPT(0, Be0, Be1, Be2, Be3);

        // t = 2p+1 (odd, buf1, Bo)
        if (p < 7) {
            LOADB(2 * p + 2, Be0, Be1, Be2, Be3);
            STAGE(2 * p + 2, 0);
            WAIT8;
        } else {
            WAIT0;
        }
        COMPT(1, Bo0, Bo1, Bo2, Bo3);
    }

#undef LOADB
#undef STAGE
#undef WAIT8
#undef WAIT0
#undef COMPT

    // C/D layout: col = lane&15, row = (lane>>4)*4 + reg. Store bf16.
    const int crow0 = (lane >> 4) * 4;
    const int ccol  = lane & 15;
#pragma unroll
    for (int mf = 0; mf < 2; ++mf)
#pragma unroll
        for (int r = 0; r < 4; ++r) {
            const int grow = block_row + wm * 32 + mf * 16 + crow0 + r;
            if (grow < M) {
                unsigned short* zr = zb + (size_t)grow * OUT_DIM + wn * 64 + ccol;
#pragma unroll
                for (int nf = 0; nf < 4; ++nf)
                    zr[nf * 16] = f2bf(acc[mf][nf][r]);
            }
        }
}

// ---------------------------------------------------------------------------
// Decode: out[e] = sigmoid( sum_k z[a_e,k]*z[b_e,k]*w3[k] ), z in bf16.
// 16 lanes per edge, 4 edges/wave, grid-stride UNROLLED x2 (2x MLP).
// ---------------------------------------------------------------------------
__device__ inline float dotw3(const uint4& ua, const uint4& ub, const f32x2* w3v) {
    const unsigned pa[4] = {ua.x, ua.y, ua.z, ua.w};
    const unsigned pb[4] = {ub.x, ub.y, ub.z, ub.w};
    f32x2 vv = (f32x2){0.f, 0.f};
#pragma unroll
    for (int i = 0; i < 4; ++i) {
        f32x2 A = (f32x2){__uint_as_float(pa[i] << 16),
                          __uint_as_float(pa[i] & 0xFFFF0000u)};
        f32x2 B = (f32x2){__uint_as_float(pb[i] << 16),
                          __uint_as_float(pb[i] & 0xFFFF0000u)};
        vv += (A * B) * w3v[i];  // v_pk_mul_f32 + v_pk_fma_f32
    }
    return vv.x + vv.y;
}

__global__ __launch_bounds__(256) void decode_kernel(const unsigned short* __restrict__ zb,
                                                     const int* __restrict__ e1,
                                                     const int* __restrict__ e2,
                                                     const float* __restrict__ w3,
                                                     float* __restrict__ out,
                                                     int E1, int E2) {
    const int tid  = threadIdx.x;
    const int lane = tid & 63;
    const int sub  = lane & 15;   // lane within 16-group
    const int sg   = lane >> 4;   // edge slot within wave (0..3)
    const int Etot = E1 + E2;
    const int nq   = (Etot + 3) >> 2;

    f32x2 w3v[4];
    {
        const float4 wlo = *(const float4*)(w3 + sub * 8);
        const float4 whi = *(const float4*)(w3 + sub * 8 + 4);
        w3v[0] = (f32x2){wlo.x, wlo.y};
        w3v[1] = (f32x2){wlo.z, wlo.w};
        w3v[2] = (f32x2){whi.x, whi.y};
        w3v[3] = (f32x2){whi.z, whi.w};
    }

    const int wave = blockIdx.x * 4 + (tid >> 6);
    const int S    = gridDim.x * 4;  // stride in quads

    for (int q = wave; q < nq; q += 2 * S) {
        const int q2    = q + S;
        const bool has2 = (q2 < nq);

        const int e_a = q * 4 + sg;
        const int e_b = has2 ? (q2 * 4 + sg) : e_a;
        const int ca  = min(e_a, Etot - 1);
        const int cb  = min(e_b, Etot - 1);

        // both index loads up front
        const int2 ia = (ca < E1) ? ((const int2*)e1)[ca] : ((const int2*)e2)[ca - E1];
        const int2 ib = (cb < E1) ? ((const int2*)e1)[cb] : ((const int2*)e2)[cb - E1];

        // all 4 row gathers issued before any math
        const uint4 a1 = *(const uint4*)(zb + (size_t)ia.x * OUT_DIM + sub * 8);
        const uint4 b1 = *(const uint4*)(zb + (size_t)ia.y * OUT_DIM + sub * 8);
        const uint4 a2 = *(const uint4*)(zb + (size_t)ib.x * OUT_DIM + sub * 8);
        const uint4 b2 = *(const uint4*)(zb + (size_t)ib.y * OUT_DIM + sub * 8);

        float v1 = dotw3(a1, b1, w3v);
        float v2 = dotw3(a2, b2, w3v);

        v1 += __shfl_xor(v1, 8);  v2 += __shfl_xor(v2, 8);
        v1 += __shfl_xor(v1, 4);  v2 += __shfl_xor(v2, 4);
        v1 += __shfl_xor(v1, 2);  v2 += __shfl_xor(v2, 2);
        v1 += __shfl_xor(v1, 1);  v2 += __shfl_xor(v2, 1);

        if (sub == 0) {
            if (e_a < Etot) out[e_a] = 1.f / (1.f + __expf(-v1));
            if (has2 && e_b < Etot) out[e_b] = 1.f / (1.f + __expf(-v2));
        }
    }
}

extern "C" void kernel_launch(void* const* d_in, const int* in_sizes, int n_in,
                              void* d_out, int out_size, void* d_ws, size_t ws_size,
                              hipStream_t stream) {
    const float* x  = (const float*)d_in[0];
    const int*   e1 = (const int*)d_in[1];
    const int*   e2 = (const int*)d_in[2];
    const float* w  = (const float*)d_in[3];
    const float* w3 = (const float*)d_in[4];

    float* out = (float*)d_out;

    const int M  = in_sizes[0] / IN_DIM;  // 100000
    const int E1 = in_sizes[1] / 2;       // 300000
    const int E2 = in_sizes[2] / 2;       // 300000

    // workspace: z_bf [M,128] bf16 (25.6 MB), then wt2 [512x128] bf16 (128 KB)
    unsigned short* zbuf = (unsigned short*)d_ws;
    unsigned short* wt2  = zbuf + (size_t)M * OUT_DIM;

    wt2_kernel<<<(IN_DIM * OUT_DIM) / 256, 256, 0, stream>>>(w, wt2);
    gemm_mfma<<<(M + BM - 1) / BM, 256, 0, stream>>>(x, wt2, zbuf, M);
    decode_kernel<<<2048, 256, 0, stream>>>(zbuf, e1, e2, w3, out, E1, E2);
}